// Round 7
// baseline (303.071 us; speedup 1.0000x reference)
//
#include <hip/hip_runtime.h>
#include <hip/hip_bf16.h>

namespace {
constexpr int N_ = 4, H_ = 512, W_ = 512, K_ = 4;
constexpr int F_ = 200000, V_ = 100000;
constexpr float SIGMA_ = 1e-4f;
constexpr float GAMMA_ = 1e-4f;
constexpr float EPS_   = 1e-10f;
constexpr float ZNEAR_ = 1.0f, ZFAR_ = 100.0f;

typedef float f32x4 __attribute__((ext_vector_type(4), aligned(4)));
typedef int   i32x4 __attribute__((ext_vector_type(4), aligned(4)));
typedef float f32x3 __attribute__((ext_vector_type(3), aligned(4)));
} // namespace

// R6 post-mortem: call-1 correct (absmax 3.9e-3), timed replays wrong
// (absmax 1.97 = normalized-random-direction = K2 read 0xAA poison in live
// fnorm rows). Execution order can't break in a captured graph (same-stream
// edge), so K1's table stores sat DIRTY in its XCD's L2 and the end-of-dispatch
// writeback was elided between graph nodes -> K2 on another XCD fetched poison
// from the coherence point (Guideline 16). Fix: compile the release INTO K1 —
// __threadfence() (agent-scope release => buffer_wbl2 + waitcnt on gfx950)
// after the table stores, plus nontemporal (no-allocate) table stores.
// Acquire side is safe: any stale line K2 holds is the previous replay's
// IDENTICAL table, never poison.

// K1: build 64B-padded per-face normal table. One thread per face.
__global__ __launch_bounds__(256) void build_fnorm_kernel(
    const float* __restrict__ vnorm,
    const int*   __restrict__ faces,
    float*       __restrict__ fnorm)   // [F][16]
{
    const int f = blockIdx.x * blockDim.x + threadIdx.x;
    if (f < F_) {
        // 16B read covers the 12B face row (4B overread stays in the page).
        const i32x4 fv = *reinterpret_cast<const i32x4*>(faces + 3 * (size_t)f);
        const f32x4 n0 = *reinterpret_cast<const f32x4*>(vnorm + 3 * (size_t)fv.x);
        const f32x4 n1 = *reinterpret_cast<const f32x4*>(vnorm + 3 * (size_t)fv.y);
        const f32x4 n2 = *reinterpret_cast<const f32x4*>(vnorm + 3 * (size_t)fv.z);
        f32x4* row = reinterpret_cast<f32x4*>(fnorm + (size_t)f * 16);
        __builtin_nontemporal_store(f32x4{n0.x, n0.y, n0.z, n1.x}, row + 0);
        __builtin_nontemporal_store(f32x4{n1.y, n1.z, n2.x, n2.y}, row + 1);
        __builtin_nontemporal_store(f32x4{n2.z, 0.f, 0.f, 0.f},    row + 2);
        // row floats 12..15 unwritten (never read by K2).
    }
    // Device-scope release: force this wave's table lines out of the XCD L2
    // before kernel completion. This is the graph-capture-proof visibility
    // guarantee for K2 (runs on arbitrary XCDs).
    __threadfence();
}

// K2: main shader. One thread per pixel; ONE 64B-line gather per live slot.
__global__ __launch_bounds__(256) void normal_shader_kernel(
    const float* __restrict__ fnorm,
    const float* __restrict__ bary,
    const float* __restrict__ dists,
    const float* __restrict__ zbuf,
    const int*   __restrict__ ptf,
    float*       __restrict__ out,
    int P)
{
    const int p = blockIdx.x * blockDim.x + threadIdx.x;
    if (p >= P) return;

    const i32x4 f4 = __builtin_nontemporal_load(reinterpret_cast<const i32x4*>(ptf) + p);
    const int fidx[4] = {f4.x, f4.y, f4.z, f4.w};
    const f32x4 dv = __builtin_nontemporal_load(reinterpret_cast<const f32x4*>(dists) + p);
    const f32x4 zv = __builtin_nontemporal_load(reinterpret_cast<const f32x4*>(zbuf) + p);
    const float d[4] = {dv.x, dv.y, dv.z, dv.w};
    const float z[4] = {zv.x, zv.y, zv.z, zv.w};

    float prob[4], zinv[4];
    float zmax = EPS_;
#pragma unroll
    for (int k = 0; k < K_; ++k) {
        const bool valid = fidx[k] >= 0;
        prob[k] = valid ? 1.0f / (1.0f + __expf(d[k] * (1.0f / SIGMA_))) : 0.0f;
        zinv[k] = valid ? (ZFAR_ - z[k]) * (1.0f / (ZFAR_ - ZNEAR_)) : 0.0f;
        zmax = fmaxf(zmax, zinv[k]);
    }
    const float delta = fmaxf(__expf((EPS_ - zmax) * (1.0f / GAMMA_)), EPS_);

    float wn[4];
#pragma unroll
    for (int k = 0; k < K_; ++k)
        wn[k] = prob[k] * __expf((zinv[k] - zmax) * (1.0f / GAMMA_));

    // Dead slots (~3 of 4) clamp to row 0: wave-broadcast line, exact 0 contrib.
    const float* rp[4];
#pragma unroll
    for (int k = 0; k < K_; ++k)
        rp[k] = fnorm + ((size_t)((wn[k] != 0.0f) ? fidx[k] : 0) << 4);

    f32x4 ra[4], rb[4], rc[4];
#pragma unroll
    for (int k = 0; k < K_; ++k) {
        ra[k] = reinterpret_cast<const f32x4*>(rp[k])[0];  // n0x n0y n0z n1x
        rb[k] = reinterpret_cast<const f32x4*>(rp[k])[1];  // n1y n1z n2x n2y
        rc[k] = reinterpret_cast<const f32x4*>(rp[k])[2];  // n2z -  -  -
    }

    const f32x4* bp = reinterpret_cast<const f32x4*>(bary + (size_t)p * 12);
    const f32x4 bA = __builtin_nontemporal_load(bp + 0);
    const f32x4 bB = __builtin_nontemporal_load(bp + 1);
    const f32x4 bC = __builtin_nontemporal_load(bp + 2);
    const float bb[12] = {bA.x, bA.y, bA.z, bA.w,
                          bB.x, bB.y, bB.z, bB.w,
                          bC.x, bC.y, bC.z, bC.w};

    float acc0 = 0.f, acc1 = 0.f, acc2 = 0.f, wsum = 0.f;
#pragma unroll
    for (int k = 0; k < K_; ++k) {
        wsum += wn[k];
        const float b0 = bb[3 * k + 0], b1 = bb[3 * k + 1], b2 = bb[3 * k + 2];
        acc0 += wn[k] * (b0 * ra[k].x + b1 * ra[k].w + b2 * rb[k].z);
        acc1 += wn[k] * (b0 * ra[k].y + b1 * rb[k].x + b2 * rb[k].w);
        acc2 += wn[k] * (b0 * ra[k].z + b1 * rb[k].y + b2 * rc[k].x);
    }

    const float inv_denom = 1.0f / (wsum + delta);
    const float r0 = (acc0 + delta) * inv_denom;   // bg = (1,1,1)
    const float r1 = (acc1 + delta) * inv_denom;
    const float r2 = (acc2 + delta) * inv_denom;
    const float nrm = fmaxf(sqrtf(r0 * r0 + r1 * r1 + r2 * r2), 1e-12f);
    const float inv = 1.0f / nrm;

    __builtin_nontemporal_store(f32x3{r0 * inv, r1 * inv, r2 * inv},
                                reinterpret_cast<f32x3*>(out + (size_t)p * 3));
}

// Fallback (proven R5 structure) if ws can't hold the table — deterministic
// choice (ws_size is fixed), so graph-capture-safe.
__global__ __launch_bounds__(256) void normal_shader_fused_kernel(
    const float* __restrict__ vnorm,
    const float* __restrict__ bary,
    const float* __restrict__ dists,
    const float* __restrict__ zbuf,
    const int*   __restrict__ faces,
    const int*   __restrict__ ptf,
    float*       __restrict__ out,
    int P)
{
    const int p = blockIdx.x * blockDim.x + threadIdx.x;
    if (p >= P) return;
    const i32x4 f4 = reinterpret_cast<const i32x4*>(ptf)[p];
    const int fidx[4] = {f4.x, f4.y, f4.z, f4.w};
    const f32x4 dv = reinterpret_cast<const f32x4*>(dists)[p];
    const f32x4 zv = reinterpret_cast<const f32x4*>(zbuf)[p];
    const float d[4] = {dv.x, dv.y, dv.z, dv.w};
    const float z[4] = {zv.x, zv.y, zv.z, zv.w};
    float prob[4], zinv[4], zmax = EPS_;
#pragma unroll
    for (int k = 0; k < K_; ++k) {
        const bool valid = fidx[k] >= 0;
        prob[k] = valid ? 1.0f / (1.0f + __expf(d[k] * (1.0f / SIGMA_))) : 0.0f;
        zinv[k] = valid ? (ZFAR_ - z[k]) * (1.0f / (ZFAR_ - ZNEAR_)) : 0.0f;
        zmax = fmaxf(zmax, zinv[k]);
    }
    const float delta = fmaxf(__expf((EPS_ - zmax) * (1.0f / GAMMA_)), EPS_);
    float wn[4];
#pragma unroll
    for (int k = 0; k < K_; ++k) wn[k] = prob[k] * __expf((zinv[k] - zmax) * (1.0f / GAMMA_));
    int cl[4];
#pragma unroll
    for (int k = 0; k < K_; ++k) cl[k] = (wn[k] != 0.0f) ? fidx[k] : 0;
    i32x4 fv[4];
#pragma unroll
    for (int k = 0; k < K_; ++k) fv[k] = *reinterpret_cast<const i32x4*>(faces + 3 * (size_t)cl[k]);
    const f32x4* bp = reinterpret_cast<const f32x4*>(bary + (size_t)p * 12);
    const f32x4 bA = bp[0], bB = bp[1], bC = bp[2];
    const float bb[12] = {bA.x, bA.y, bA.z, bA.w, bB.x, bB.y, bB.z, bB.w, bC.x, bC.y, bC.z, bC.w};
    f32x4 n0[4], n1[4], n2[4];
#pragma unroll
    for (int k = 0; k < K_; ++k) {
        n0[k] = *reinterpret_cast<const f32x4*>(vnorm + 3 * (size_t)fv[k].x);
        n1[k] = *reinterpret_cast<const f32x4*>(vnorm + 3 * (size_t)fv[k].y);
        n2[k] = *reinterpret_cast<const f32x4*>(vnorm + 3 * (size_t)fv[k].z);
    }
    float acc0 = 0.f, acc1 = 0.f, acc2 = 0.f, wsum = 0.f;
#pragma unroll
    for (int k = 0; k < K_; ++k) {
        wsum += wn[k];
        const float b0 = bb[3 * k], b1 = bb[3 * k + 1], b2 = bb[3 * k + 2];
        acc0 += wn[k] * (b0 * n0[k].x + b1 * n1[k].x + b2 * n2[k].x);
        acc1 += wn[k] * (b0 * n0[k].y + b1 * n1[k].y + b2 * n2[k].y);
        acc2 += wn[k] * (b0 * n0[k].z + b1 * n1[k].z + b2 * n2[k].z);
    }
    const float inv_denom = 1.0f / (wsum + delta);
    const float r0 = (acc0 + delta) * inv_denom;
    const float r1 = (acc1 + delta) * inv_denom;
    const float r2 = (acc2 + delta) * inv_denom;
    const float nrm = fmaxf(sqrtf(r0 * r0 + r1 * r1 + r2 * r2), 1e-12f);
    const float inv = 1.0f / nrm;
    float* op = out + (size_t)p * 3;
    op[0] = r0 * inv; op[1] = r1 * inv; op[2] = r2 * inv;
}

extern "C" void kernel_launch(void* const* d_in, const int* in_sizes, int n_in,
                              void* d_out, int out_size, void* d_ws, size_t ws_size,
                              hipStream_t stream) {
    // setup_inputs order: verts(0, unused), vertex_normals(1), bary_coords(2),
    // dists(3), zbuf(4), faces(5), pix_to_face(6)
    const float* vnorm = (const float*)d_in[1];
    const float* bary  = (const float*)d_in[2];
    const float* dists = (const float*)d_in[3];
    const float* zbuf  = (const float*)d_in[4];
    const int*   faces = (const int*)d_in[5];
    const int*   ptf   = (const int*)d_in[6];
    float*       out   = (float*)d_out;

    const int P = N_ * H_ * W_;
    const size_t table_bytes = (size_t)F_ * 16 * sizeof(float);  // 12.8 MB

    if (ws_size >= table_bytes) {
        float* fnorm = (float*)d_ws;
        hipLaunchKernelGGL(build_fnorm_kernel,
                           dim3((F_ + 255) / 256), dim3(256), 0, stream,
                           vnorm, faces, fnorm);
        hipLaunchKernelGGL(normal_shader_kernel,
                           dim3((P + 255) / 256), dim3(256), 0, stream,
                           fnorm, bary, dists, zbuf, ptf, out, P);
    } else {
        hipLaunchKernelGGL(normal_shader_fused_kernel,
                           dim3((P + 255) / 256), dim3(256), 0, stream,
                           vnorm, bary, dists, zbuf, faces, ptf, out, P);
    }
}

// Round 8
// 173.626 us; speedup vs baseline: 1.7455x; 1.7455x over previous
//
#include <hip/hip_runtime.h>
#include <hip/hip_bf16.h>

namespace {
constexpr int N_ = 4, H_ = 512, W_ = 512, K_ = 4;
constexpr int F_ = 200000, V_ = 100000;
constexpr float SIGMA_ = 1e-4f;
constexpr float GAMMA_ = 1e-4f;
constexpr float EPS_   = 1e-10f;
constexpr float ZNEAR_ = 1.0f, ZFAR_ = 100.0f;

typedef float f32x4 __attribute__((ext_vector_type(4), aligned(4)));
typedef int   i32x4 __attribute__((ext_vector_type(4), aligned(4)));
typedef float f32x3 __attribute__((ext_vector_type(3), aligned(4)));
} // namespace

// R7 post-mortem: __threadfence() per wave = full-L2 writeback per wave ->
// K1 155us (VALUBusy 0.05%). But K2 dropped 52->36us (line model confirmed)
// and the harness has ~112us fixed overhead (R3..R5: dur_us - kernel ~ 104-112).
// This round: replace the fence with per-store agent-scope relaxed atomic
// stores (8B, -> global_store sc1 = write-through past the non-coherent XCD
// L2 to the device coherence point). No dirty L2 lines exist at K1 end, so
// nothing relies on the elided inter-node cache flush. K2-side staleness is
// benign: any cached table line is the previous replay's IDENTICAL table.

__device__ __forceinline__ void store_agent_f2(float* dst, float a, float b) {
    union { float f[2]; unsigned long long u; } pk;
    pk.f[0] = a; pk.f[1] = b;
    __hip_atomic_store(reinterpret_cast<unsigned long long*>(dst), pk.u,
                       __ATOMIC_RELAXED, __HIP_MEMORY_SCOPE_AGENT);
}

// K1: build 64B-padded per-face normal table. One thread per face.
// Row f (16 floats): [n0x n0y n0z n1x n1y n1z n2x n2y n2z 0 0 0 | pad]
__global__ __launch_bounds__(256) void build_fnorm_kernel(
    const float* __restrict__ vnorm,
    const int*   __restrict__ faces,
    float*       __restrict__ fnorm)   // [F][16]
{
    const int f = blockIdx.x * blockDim.x + threadIdx.x;
    if (f >= F_) return;
    // 16B read covers the 12B face row (4B overread stays in the page).
    const i32x4 fv = *reinterpret_cast<const i32x4*>(faces + 3 * (size_t)f);
    const f32x4 n0 = *reinterpret_cast<const f32x4*>(vnorm + 3 * (size_t)fv.x);
    const f32x4 n1 = *reinterpret_cast<const f32x4*>(vnorm + 3 * (size_t)fv.y);
    const f32x4 n2 = *reinterpret_cast<const f32x4*>(vnorm + 3 * (size_t)fv.z);
    float* row = fnorm + (size_t)f * 16;
    store_agent_f2(row +  0, n0.x, n0.y);
    store_agent_f2(row +  2, n0.z, n1.x);
    store_agent_f2(row +  4, n1.y, n1.z);
    store_agent_f2(row +  6, n2.x, n2.y);
    store_agent_f2(row +  8, n2.z, 0.f);
    store_agent_f2(row + 10, 0.f,  0.f);
    // floats 12..15 left unwritten (never read by K2).
}

// K2: main shader. One thread per pixel; ONE 64B-line gather per live slot.
__global__ __launch_bounds__(256) void normal_shader_kernel(
    const float* __restrict__ fnorm,
    const float* __restrict__ bary,
    const float* __restrict__ dists,
    const float* __restrict__ zbuf,
    const int*   __restrict__ ptf,
    float*       __restrict__ out,
    int P)
{
    const int p = blockIdx.x * blockDim.x + threadIdx.x;
    if (p >= P) return;

    const i32x4 f4 = __builtin_nontemporal_load(reinterpret_cast<const i32x4*>(ptf) + p);
    const int fidx[4] = {f4.x, f4.y, f4.z, f4.w};
    const f32x4 dv = __builtin_nontemporal_load(reinterpret_cast<const f32x4*>(dists) + p);
    const f32x4 zv = __builtin_nontemporal_load(reinterpret_cast<const f32x4*>(zbuf) + p);
    const float d[4] = {dv.x, dv.y, dv.z, dv.w};
    const float z[4] = {zv.x, zv.y, zv.z, zv.w};

    float prob[4], zinv[4];
    float zmax = EPS_;
#pragma unroll
    for (int k = 0; k < K_; ++k) {
        const bool valid = fidx[k] >= 0;
        prob[k] = valid ? 1.0f / (1.0f + __expf(d[k] * (1.0f / SIGMA_))) : 0.0f;
        zinv[k] = valid ? (ZFAR_ - z[k]) * (1.0f / (ZFAR_ - ZNEAR_)) : 0.0f;
        zmax = fmaxf(zmax, zinv[k]);
    }
    const float delta = fmaxf(__expf((EPS_ - zmax) * (1.0f / GAMMA_)), EPS_);

    float wn[4];
#pragma unroll
    for (int k = 0; k < K_; ++k)
        wn[k] = prob[k] * __expf((zinv[k] - zmax) * (1.0f / GAMMA_));

    // Dead slots (~3 of 4) clamp to row 0: wave-broadcast line, exact 0 contrib.
    const float* rp[4];
#pragma unroll
    for (int k = 0; k < K_; ++k)
        rp[k] = fnorm + ((size_t)((wn[k] != 0.0f) ? fidx[k] : 0) << 4);

    f32x4 ra[4], rb[4], rc[4];
#pragma unroll
    for (int k = 0; k < K_; ++k) {
        ra[k] = reinterpret_cast<const f32x4*>(rp[k])[0];  // n0x n0y n0z n1x
        rb[k] = reinterpret_cast<const f32x4*>(rp[k])[1];  // n1y n1z n2x n2y
        rc[k] = reinterpret_cast<const f32x4*>(rp[k])[2];  // n2z 0 0 0
    }

    const f32x4* bp = reinterpret_cast<const f32x4*>(bary + (size_t)p * 12);
    const f32x4 bA = __builtin_nontemporal_load(bp + 0);
    const f32x4 bB = __builtin_nontemporal_load(bp + 1);
    const f32x4 bC = __builtin_nontemporal_load(bp + 2);
    const float bb[12] = {bA.x, bA.y, bA.z, bA.w,
                          bB.x, bB.y, bB.z, bB.w,
                          bC.x, bC.y, bC.z, bC.w};

    float acc0 = 0.f, acc1 = 0.f, acc2 = 0.f, wsum = 0.f;
#pragma unroll
    for (int k = 0; k < K_; ++k) {
        wsum += wn[k];
        const float b0 = bb[3 * k + 0], b1 = bb[3 * k + 1], b2 = bb[3 * k + 2];
        acc0 += wn[k] * (b0 * ra[k].x + b1 * ra[k].w + b2 * rb[k].z);
        acc1 += wn[k] * (b0 * ra[k].y + b1 * rb[k].x + b2 * rb[k].w);
        acc2 += wn[k] * (b0 * ra[k].z + b1 * rb[k].y + b2 * rc[k].x);
    }

    const float inv_denom = 1.0f / (wsum + delta);
    const float r0 = (acc0 + delta) * inv_denom;   // bg = (1,1,1)
    const float r1 = (acc1 + delta) * inv_denom;
    const float r2 = (acc2 + delta) * inv_denom;
    const float nrm = fmaxf(sqrtf(r0 * r0 + r1 * r1 + r2 * r2), 1e-12f);
    const float inv = 1.0f / nrm;

    __builtin_nontemporal_store(f32x3{r0 * inv, r1 * inv, r2 * inv},
                                reinterpret_cast<f32x3*>(out + (size_t)p * 3));
}

// Fallback (proven R5 structure) if ws can't hold the table — deterministic
// choice (ws_size is fixed), so graph-capture-safe.
__global__ __launch_bounds__(256) void normal_shader_fused_kernel(
    const float* __restrict__ vnorm,
    const float* __restrict__ bary,
    const float* __restrict__ dists,
    const float* __restrict__ zbuf,
    const int*   __restrict__ faces,
    const int*   __restrict__ ptf,
    float*       __restrict__ out,
    int P)
{
    const int p = blockIdx.x * blockDim.x + threadIdx.x;
    if (p >= P) return;
    const i32x4 f4 = reinterpret_cast<const i32x4*>(ptf)[p];
    const int fidx[4] = {f4.x, f4.y, f4.z, f4.w};
    const f32x4 dv = reinterpret_cast<const f32x4*>(dists)[p];
    const f32x4 zv = reinterpret_cast<const f32x4*>(zbuf)[p];
    const float d[4] = {dv.x, dv.y, dv.z, dv.w};
    const float z[4] = {zv.x, zv.y, zv.z, zv.w};
    float prob[4], zinv[4], zmax = EPS_;
#pragma unroll
    for (int k = 0; k < K_; ++k) {
        const bool valid = fidx[k] >= 0;
        prob[k] = valid ? 1.0f / (1.0f + __expf(d[k] * (1.0f / SIGMA_))) : 0.0f;
        zinv[k] = valid ? (ZFAR_ - z[k]) * (1.0f / (ZFAR_ - ZNEAR_)) : 0.0f;
        zmax = fmaxf(zmax, zinv[k]);
    }
    const float delta = fmaxf(__expf((EPS_ - zmax) * (1.0f / GAMMA_)), EPS_);
    float wn[4];
#pragma unroll
    for (int k = 0; k < K_; ++k) wn[k] = prob[k] * __expf((zinv[k] - zmax) * (1.0f / GAMMA_));
    int cl[4];
#pragma unroll
    for (int k = 0; k < K_; ++k) cl[k] = (wn[k] != 0.0f) ? fidx[k] : 0;
    i32x4 fv[4];
#pragma unroll
    for (int k = 0; k < K_; ++k) fv[k] = *reinterpret_cast<const i32x4*>(faces + 3 * (size_t)cl[k]);
    const f32x4* bp = reinterpret_cast<const f32x4*>(bary + (size_t)p * 12);
    const f32x4 bA = bp[0], bB = bp[1], bC = bp[2];
    const float bb[12] = {bA.x, bA.y, bA.z, bA.w, bB.x, bB.y, bB.z, bB.w, bC.x, bC.y, bC.z, bC.w};
    f32x4 n0[4], n1[4], n2[4];
#pragma unroll
    for (int k = 0; k < K_; ++k) {
        n0[k] = *reinterpret_cast<const f32x4*>(vnorm + 3 * (size_t)fv[k].x);
        n1[k] = *reinterpret_cast<const f32x4*>(vnorm + 3 * (size_t)fv[k].y);
        n2[k] = *reinterpret_cast<const f32x4*>(vnorm + 3 * (size_t)fv[k].z);
    }
    float acc0 = 0.f, acc1 = 0.f, acc2 = 0.f, wsum = 0.f;
#pragma unroll
    for (int k = 0; k < K_; ++k) {
        wsum += wn[k];
        const float b0 = bb[3 * k], b1 = bb[3 * k + 1], b2 = bb[3 * k + 2];
        acc0 += wn[k] * (b0 * n0[k].x + b1 * n1[k].x + b2 * n2[k].x);
        acc1 += wn[k] * (b0 * n0[k].y + b1 * n1[k].y + b2 * n2[k].y);
        acc2 += wn[k] * (b0 * n0[k].z + b1 * n1[k].z + b2 * n2[k].z);
    }
    const float inv_denom = 1.0f / (wsum + delta);
    const float r0 = (acc0 + delta) * inv_denom;
    const float r1 = (acc1 + delta) * inv_denom;
    const float r2 = (acc2 + delta) * inv_denom;
    const float nrm = fmaxf(sqrtf(r0 * r0 + r1 * r1 + r2 * r2), 1e-12f);
    const float inv = 1.0f / nrm;
    float* op = out + (size_t)p * 3;
    op[0] = r0 * inv; op[1] = r1 * inv; op[2] = r2 * inv;
}

extern "C" void kernel_launch(void* const* d_in, const int* in_sizes, int n_in,
                              void* d_out, int out_size, void* d_ws, size_t ws_size,
                              hipStream_t stream) {
    // setup_inputs order: verts(0, unused), vertex_normals(1), bary_coords(2),
    // dists(3), zbuf(4), faces(5), pix_to_face(6)
    const float* vnorm = (const float*)d_in[1];
    const float* bary  = (const float*)d_in[2];
    const float* dists = (const float*)d_in[3];
    const float* zbuf  = (const float*)d_in[4];
    const int*   faces = (const int*)d_in[5];
    const int*   ptf   = (const int*)d_in[6];
    float*       out   = (float*)d_out;

    const int P = N_ * H_ * W_;
    const size_t table_bytes = (size_t)F_ * 16 * sizeof(float);  // 12.8 MB

    if (ws_size >= table_bytes) {
        float* fnorm = (float*)d_ws;
        hipLaunchKernelGGL(build_fnorm_kernel,
                           dim3((F_ + 255) / 256), dim3(256), 0, stream,
                           vnorm, faces, fnorm);
        hipLaunchKernelGGL(normal_shader_kernel,
                           dim3((P + 255) / 256), dim3(256), 0, stream,
                           fnorm, bary, dists, zbuf, ptf, out, P);
    } else {
        hipLaunchKernelGGL(normal_shader_fused_kernel,
                           dim3((P + 255) / 256), dim3(256), 0, stream,
                           vnorm, bary, dists, zbuf, faces, ptf, out, P);
    }
}

// Round 9
// 153.520 us; speedup vs baseline: 1.9741x; 1.1310x over previous
//
#include <hip/hip_runtime.h>
#include <hip/hip_bf16.h>
#include <hip/hip_fp16.h>

namespace {
constexpr int N_ = 4, H_ = 512, W_ = 512, K_ = 4;
constexpr int F_ = 200000;
constexpr float SIGMA_ = 1e-4f;
constexpr float GAMMA_ = 1e-4f;
constexpr float EPS_   = 1e-10f;
constexpr float ZNEAR_ = 1.0f, ZFAR_ = 100.0f;

typedef float    f32x4 __attribute__((ext_vector_type(4), aligned(4)));
typedef int      i32x4 __attribute__((ext_vector_type(4), aligned(4)));
typedef float    f32x3 __attribute__((ext_vector_type(3), aligned(4)));
typedef _Float16 f16x8 __attribute__((ext_vector_type(8), aligned(4)));
typedef _Float16 f16x2 __attribute__((ext_vector_type(2), aligned(4)));
} // namespace

// R8 post-mortem: table cut K2 52->42us but 12.8MB table misses the 4MiB
// per-XCD L2 (FETCH +40MB, per-line cost 5->9cyc = L3 depth). Residual =
// MLP starvation on L3-latency gathers. This round: (1) fp16 table, 32B rows
// -> 6.4MB (halves gather+K1 bytes, ~60% L2-resident; fp16 err 5e-4 << 2e-2
// threshold); (2) 2px/thread (p, p+P/2) -> 8 gathers in flight per thread.
// K1 release mechanism unchanged: agent-scope relaxed atomic stores (sc1
// write-through past the non-coherent XCD L2) — proven in R8.

// K1: fnorm[f] = 32B row {fp16 n0x n0y n0z n1x n1y n1z n2x n2y n2z pad...}
__global__ __launch_bounds__(256) void build_fnorm_kernel(
    const float* __restrict__ vnorm,
    const int*   __restrict__ faces,
    _Float16*    __restrict__ fnorm)   // [F][16] halves
{
    const int f = blockIdx.x * blockDim.x + threadIdx.x;
    if (f >= F_) return;
    // 16B read covers the 12B face row (4B overread stays in the page).
    const i32x4 fv = *reinterpret_cast<const i32x4*>(faces + 3 * (size_t)f);
    const f32x4 n0 = *reinterpret_cast<const f32x4*>(vnorm + 3 * (size_t)fv.x);
    const f32x4 n1 = *reinterpret_cast<const f32x4*>(vnorm + 3 * (size_t)fv.y);
    const f32x4 n2 = *reinterpret_cast<const f32x4*>(vnorm + 3 * (size_t)fv.z);
    union { _Float16 h[12]; unsigned long long u[3]; } pk;
    pk.h[0] = (_Float16)n0.x; pk.h[1] = (_Float16)n0.y; pk.h[2] = (_Float16)n0.z;
    pk.h[3] = (_Float16)n1.x; pk.h[4] = (_Float16)n1.y; pk.h[5] = (_Float16)n1.z;
    pk.h[6] = (_Float16)n2.x; pk.h[7] = (_Float16)n2.y; pk.h[8] = (_Float16)n2.z;
    pk.h[9] = pk.h[10] = pk.h[11] = (_Float16)0.f;
    unsigned long long* dst =
        reinterpret_cast<unsigned long long*>(fnorm + (size_t)f * 16);
    __hip_atomic_store(dst + 0, pk.u[0], __ATOMIC_RELAXED, __HIP_MEMORY_SCOPE_AGENT);
    __hip_atomic_store(dst + 1, pk.u[1], __ATOMIC_RELAXED, __HIP_MEMORY_SCOPE_AGENT);
    __hip_atomic_store(dst + 2, pk.u[2], __ATOMIC_RELAXED, __HIP_MEMORY_SCOPE_AGENT);
    // halves 12..15 unwritten (never read by K2).
}

// K2: 2 pixels/thread (t and t+P/2); one 64B-line gather per live slot.
__global__ __launch_bounds__(256) void normal_shader_kernel(
    const _Float16* __restrict__ fnorm,
    const float*    __restrict__ bary,
    const float*    __restrict__ dists,
    const float*    __restrict__ zbuf,
    const int*      __restrict__ ptf,
    float*          __restrict__ out,
    int P)
{
    const int t = blockIdx.x * blockDim.x + threadIdx.x;
    const int halfP = P >> 1;
    if (t >= halfP) return;
    const int pp[2] = {t, t + halfP};

    // ---- Phase A: all streaming loads for both pixels (independent) ----
    i32x4 f4[2]; f32x4 dv[2], zv[2], bA[2], bB[2], bC[2];
#pragma unroll
    for (int j = 0; j < 2; ++j) {
        const int p = pp[j];
        f4[j] = __builtin_nontemporal_load(reinterpret_cast<const i32x4*>(ptf) + p);
        dv[j] = __builtin_nontemporal_load(reinterpret_cast<const f32x4*>(dists) + p);
        zv[j] = __builtin_nontemporal_load(reinterpret_cast<const f32x4*>(zbuf) + p);
        const f32x4* bp = reinterpret_cast<const f32x4*>(bary + (size_t)p * 12);
        bA[j] = __builtin_nontemporal_load(bp + 0);
        bB[j] = __builtin_nontemporal_load(bp + 1);
        bC[j] = __builtin_nontemporal_load(bp + 2);
    }

    // ---- Phase B: weights + gather pointers for both pixels ----
    float wn[2][4], delta[2];
    const _Float16* rp[2][4];
#pragma unroll
    for (int j = 0; j < 2; ++j) {
        const int fidx[4] = {f4[j].x, f4[j].y, f4[j].z, f4[j].w};
        const float d[4] = {dv[j].x, dv[j].y, dv[j].z, dv[j].w};
        const float z[4] = {zv[j].x, zv[j].y, zv[j].z, zv[j].w};
        float prob[4], zinv[4], zmax = EPS_;
#pragma unroll
        for (int k = 0; k < K_; ++k) {
            const bool valid = fidx[k] >= 0;
            prob[k] = valid ? 1.0f / (1.0f + __expf(d[k] * (1.0f / SIGMA_))) : 0.0f;
            zinv[k] = valid ? (ZFAR_ - z[k]) * (1.0f / (ZFAR_ - ZNEAR_)) : 0.0f;
            zmax = fmaxf(zmax, zinv[k]);
        }
        delta[j] = fmaxf(__expf((EPS_ - zmax) * (1.0f / GAMMA_)), EPS_);
#pragma unroll
        for (int k = 0; k < K_; ++k) {
            wn[j][k] = prob[k] * __expf((zinv[k] - zmax) * (1.0f / GAMMA_));
            // Dead slots clamp to row 0: wave-broadcast line, exact 0 contrib.
            rp[j][k] = fnorm + ((size_t)((wn[j][k] != 0.0f) ? fidx[k] : 0) << 4);
        }
    }

    // ---- Phase C: all 8 slot gathers in flight (16B + 4B per slot) ----
    f16x8 A[2][4]; f16x2 C[2][4];
#pragma unroll
    for (int j = 0; j < 2; ++j)
#pragma unroll
        for (int k = 0; k < K_; ++k) {
            A[j][k] = *reinterpret_cast<const f16x8*>(rp[j][k]);      // h0..h7
            C[j][k] = *reinterpret_cast<const f16x2*>(rp[j][k] + 8);  // h8,pad
        }

    // ---- Phase D: math + store ----
#pragma unroll
    for (int j = 0; j < 2; ++j) {
        const float bb[12] = {bA[j].x, bA[j].y, bA[j].z, bA[j].w,
                              bB[j].x, bB[j].y, bB[j].z, bB[j].w,
                              bC[j].x, bC[j].y, bC[j].z, bC[j].w};
        float acc0 = 0.f, acc1 = 0.f, acc2 = 0.f, wsum = 0.f;
#pragma unroll
        for (int k = 0; k < K_; ++k) {
            const float w = wn[j][k];
            wsum += w;
            const float b0 = bb[3 * k + 0], b1 = bb[3 * k + 1], b2 = bb[3 * k + 2];
            acc0 += w * (b0 * (float)A[j][k][0] + b1 * (float)A[j][k][3] + b2 * (float)A[j][k][6]);
            acc1 += w * (b0 * (float)A[j][k][1] + b1 * (float)A[j][k][4] + b2 * (float)A[j][k][7]);
            acc2 += w * (b0 * (float)A[j][k][2] + b1 * (float)A[j][k][5] + b2 * (float)C[j][k][0]);
        }
        const float inv_denom = 1.0f / (wsum + delta[j]);
        const float r0 = (acc0 + delta[j]) * inv_denom;   // bg = (1,1,1)
        const float r1 = (acc1 + delta[j]) * inv_denom;
        const float r2 = (acc2 + delta[j]) * inv_denom;
        const float nrm = fmaxf(sqrtf(r0 * r0 + r1 * r1 + r2 * r2), 1e-12f);
        const float inv = 1.0f / nrm;
        __builtin_nontemporal_store(
            f32x3{r0 * inv, r1 * inv, r2 * inv},
            reinterpret_cast<f32x3*>(out + (size_t)pp[j] * 3));
    }
}

// Fallback (proven R5 structure) if ws can't hold the table.
__global__ __launch_bounds__(256) void normal_shader_fused_kernel(
    const float* __restrict__ vnorm,
    const float* __restrict__ bary,
    const float* __restrict__ dists,
    const float* __restrict__ zbuf,
    const int*   __restrict__ faces,
    const int*   __restrict__ ptf,
    float*       __restrict__ out,
    int P)
{
    const int p = blockIdx.x * blockDim.x + threadIdx.x;
    if (p >= P) return;
    const i32x4 f4 = reinterpret_cast<const i32x4*>(ptf)[p];
    const int fidx[4] = {f4.x, f4.y, f4.z, f4.w};
    const f32x4 dv = reinterpret_cast<const f32x4*>(dists)[p];
    const f32x4 zv = reinterpret_cast<const f32x4*>(zbuf)[p];
    const float d[4] = {dv.x, dv.y, dv.z, dv.w};
    const float z[4] = {zv.x, zv.y, zv.z, zv.w};
    float prob[4], zinv[4], zmax = EPS_;
#pragma unroll
    for (int k = 0; k < K_; ++k) {
        const bool valid = fidx[k] >= 0;
        prob[k] = valid ? 1.0f / (1.0f + __expf(d[k] * (1.0f / SIGMA_))) : 0.0f;
        zinv[k] = valid ? (ZFAR_ - z[k]) * (1.0f / (ZFAR_ - ZNEAR_)) : 0.0f;
        zmax = fmaxf(zmax, zinv[k]);
    }
    const float delta = fmaxf(__expf((EPS_ - zmax) * (1.0f / GAMMA_)), EPS_);
    float wn[4];
#pragma unroll
    for (int k = 0; k < K_; ++k) wn[k] = prob[k] * __expf((zinv[k] - zmax) * (1.0f / GAMMA_));
    int cl[4];
#pragma unroll
    for (int k = 0; k < K_; ++k) cl[k] = (wn[k] != 0.0f) ? fidx[k] : 0;
    i32x4 fv[4];
#pragma unroll
    for (int k = 0; k < K_; ++k) fv[k] = *reinterpret_cast<const i32x4*>(faces + 3 * (size_t)cl[k]);
    const f32x4* bp = reinterpret_cast<const f32x4*>(bary + (size_t)p * 12);
    const f32x4 bA = bp[0], bB = bp[1], bC = bp[2];
    const float bb[12] = {bA.x, bA.y, bA.z, bA.w, bB.x, bB.y, bB.z, bB.w, bC.x, bC.y, bC.z, bC.w};
    f32x4 n0[4], n1[4], n2[4];
#pragma unroll
    for (int k = 0; k < K_; ++k) {
        n0[k] = *reinterpret_cast<const f32x4*>(vnorm + 3 * (size_t)fv[k].x);
        n1[k] = *reinterpret_cast<const f32x4*>(vnorm + 3 * (size_t)fv[k].y);
        n2[k] = *reinterpret_cast<const f32x4*>(vnorm + 3 * (size_t)fv[k].z);
    }
    float acc0 = 0.f, acc1 = 0.f, acc2 = 0.f, wsum = 0.f;
#pragma unroll
    for (int k = 0; k < K_; ++k) {
        wsum += wn[k];
        const float b0 = bb[3 * k], b1 = bb[3 * k + 1], b2 = bb[3 * k + 2];
        acc0 += wn[k] * (b0 * n0[k].x + b1 * n1[k].x + b2 * n2[k].x);
        acc1 += wn[k] * (b0 * n0[k].y + b1 * n1[k].y + b2 * n2[k].y);
        acc2 += wn[k] * (b0 * n0[k].z + b1 * n1[k].z + b2 * n2[k].z);
    }
    const float inv_denom = 1.0f / (wsum + delta);
    const float r0 = (acc0 + delta) * inv_denom;
    const float r1 = (acc1 + delta) * inv_denom;
    const float r2 = (acc2 + delta) * inv_denom;
    const float nrm = fmaxf(sqrtf(r0 * r0 + r1 * r1 + r2 * r2), 1e-12f);
    const float inv = 1.0f / nrm;
    float* op = out + (size_t)p * 3;
    op[0] = r0 * inv; op[1] = r1 * inv; op[2] = r2 * inv;
}

extern "C" void kernel_launch(void* const* d_in, const int* in_sizes, int n_in,
                              void* d_out, int out_size, void* d_ws, size_t ws_size,
                              hipStream_t stream) {
    // setup_inputs order: verts(0, unused), vertex_normals(1), bary_coords(2),
    // dists(3), zbuf(4), faces(5), pix_to_face(6)
    const float* vnorm = (const float*)d_in[1];
    const float* bary  = (const float*)d_in[2];
    const float* dists = (const float*)d_in[3];
    const float* zbuf  = (const float*)d_in[4];
    const int*   faces = (const int*)d_in[5];
    const int*   ptf   = (const int*)d_in[6];
    float*       out   = (float*)d_out;

    const int P = N_ * H_ * W_;
    const size_t table_bytes = (size_t)F_ * 16 * sizeof(_Float16);  // 6.4 MB

    if (ws_size >= table_bytes) {
        _Float16* fnorm = (_Float16*)d_ws;
        hipLaunchKernelGGL(build_fnorm_kernel,
                           dim3((F_ + 255) / 256), dim3(256), 0, stream,
                           vnorm, faces, fnorm);
        hipLaunchKernelGGL(normal_shader_kernel,
                           dim3(((P >> 1) + 255) / 256), dim3(256), 0, stream,
                           fnorm, bary, dists, zbuf, ptf, out, P);
    } else {
        hipLaunchKernelGGL(normal_shader_fused_kernel,
                           dim3((P + 255) / 256), dim3(256), 0, stream,
                           vnorm, bary, dists, zbuf, faces, ptf, out, P);
    }
}

// Round 11
// 152.941 us; speedup vs baseline: 1.9816x; 1.0038x over previous
//
#include <hip/hip_runtime.h>
#include <hip/hip_bf16.h>

namespace {
constexpr int N_ = 4, H_ = 512, W_ = 512, K_ = 4;
constexpr int F_ = 200000;
constexpr float SIGMA_ = 1e-4f;
constexpr float GAMMA_ = 1e-4f;
constexpr float EPS_   = 1e-10f;
constexpr float ZNEAR_ = 1.0f, ZFAR_ = 100.0f;

typedef float        f32x4 __attribute__((ext_vector_type(4), aligned(4)));
typedef int          i32x4 __attribute__((ext_vector_type(4), aligned(4)));
typedef float        f32x3 __attribute__((ext_vector_type(3), aligned(4)));
typedef unsigned int u32x4 __attribute__((ext_vector_type(4), aligned(16)));
} // namespace

// R10 post-mortem: absmax exactly 2.0 on call 1 = z<0 hemisphere normals
// decoded opposite -> ENCODE wrap was wrong (used decode-style subtract
// px -= copysign(-pz,px) => sign(px)(2|px|+|py|-1) instead of the standard
// (1-|py|)sign(px)). Decode was algebraically correct. Fix: standard encode
// wrap. Table concept unchanged from R9: oct16 rows (16B, 3.2MB, fully
// L2-resident per XCD), ~1e-4/component accuracy (5x better than fp16),
// K1 release via agent-scope relaxed atomic stores (write-through, proven R8).

__device__ __forceinline__ unsigned int oct_encode(float x, float y, float z) {
    const float inv = 1.0f / (fabsf(x) + fabsf(y) + fabsf(z)); // unit input
    const float px = x * inv, py = y * inv, pz = z * inv;
    // Standard octahedral wrap for the z<0 hemisphere: (1-|p.yx|)*sign(p.xy)
    const float wx = (1.0f - fabsf(py)) * copysignf(1.0f, px);
    const float wy = (1.0f - fabsf(px)) * copysignf(1.0f, py);
    const bool neg = pz < 0.0f;
    const float ex = neg ? wx : px;
    const float ey = neg ? wy : py;
    const int ix = (int)rintf(ex * 32767.0f);
    const int iy = (int)rintf(ey * 32767.0f);
    return ((unsigned int)ix & 0xffffu) | (((unsigned int)iy & 0xffffu) << 16);
}

__device__ __forceinline__ f32x3 oct_decode(unsigned int e) {
    const float fx = (float)(short)(unsigned short)(e & 0xffffu) * (1.0f / 32767.0f);
    const float fy = (float)(short)(unsigned short)(e >> 16)     * (1.0f / 32767.0f);
    const float z  = 1.0f - fabsf(fx) - fabsf(fy);
    const float t  = fmaxf(-z, 0.0f);
    // fx - copysign(t,fx) == sign(fx)*(1-|fy|) when z<0  (verified algebra)
    const float x  = fx - copysignf(t, fx);
    const float y  = fy - copysignf(t, fy);
    const float inv = rsqrtf(x * x + y * y + z * z);
    return f32x3{x * inv, y * inv, z * inv};
}

// K1: fnorm row f (16B): {oct16(n0), oct16(n1), oct16(n2), pad} — written via
// two 8B agent-scope relaxed atomics (write-through; no dirty XCD-L2 lines).
__global__ __launch_bounds__(256) void build_fnorm_kernel(
    const float*  __restrict__ vnorm,
    const int*    __restrict__ faces,
    unsigned int* __restrict__ fnorm)   // [F][4] u32
{
    const int f = blockIdx.x * blockDim.x + threadIdx.x;
    if (f >= F_) return;
    // 16B read covers the 12B face row (4B overread stays in the page).
    const i32x4 fv = *reinterpret_cast<const i32x4*>(faces + 3 * (size_t)f);
    const f32x4 n0 = *reinterpret_cast<const f32x4*>(vnorm + 3 * (size_t)fv.x);
    const f32x4 n1 = *reinterpret_cast<const f32x4*>(vnorm + 3 * (size_t)fv.y);
    const f32x4 n2 = *reinterpret_cast<const f32x4*>(vnorm + 3 * (size_t)fv.z);
    const unsigned long long e0 = oct_encode(n0.x, n0.y, n0.z);
    const unsigned long long e1 = oct_encode(n1.x, n1.y, n1.z);
    const unsigned long long e2 = oct_encode(n2.x, n2.y, n2.z);
    unsigned long long* dst =
        reinterpret_cast<unsigned long long*>(fnorm + (size_t)f * 4);
    __hip_atomic_store(dst + 0, e0 | (e1 << 32), __ATOMIC_RELAXED, __HIP_MEMORY_SCOPE_AGENT);
    __hip_atomic_store(dst + 1, e2,              __ATOMIC_RELAXED, __HIP_MEMORY_SCOPE_AGENT);
}

// K2: 2 pixels/thread (t, t+P/2); ONE 16B gather per slot from the 3.2MB
// L2-resident table; branch-free decode (dead slots clamp to row 0, wn==0
// kills the contribution exactly — bit-equivalent to reference).
__global__ __launch_bounds__(256) void normal_shader_kernel(
    const unsigned int* __restrict__ fnorm,
    const float*        __restrict__ bary,
    const float*        __restrict__ dists,
    const float*        __restrict__ zbuf,
    const int*          __restrict__ ptf,
    float*              __restrict__ out,
    int P)
{
    const int t = blockIdx.x * blockDim.x + threadIdx.x;
    const int halfP = P >> 1;
    if (t >= halfP) return;
    const int pp[2] = {t, t + halfP};

    // ---- Phase A: all streaming loads for both pixels (independent) ----
    i32x4 f4[2]; f32x4 dv[2], zv[2], bA[2], bB[2], bC[2];
#pragma unroll
    for (int j = 0; j < 2; ++j) {
        const int p = pp[j];
        f4[j] = __builtin_nontemporal_load(reinterpret_cast<const i32x4*>(ptf) + p);
        dv[j] = __builtin_nontemporal_load(reinterpret_cast<const f32x4*>(dists) + p);
        zv[j] = __builtin_nontemporal_load(reinterpret_cast<const f32x4*>(zbuf) + p);
        const f32x4* bp = reinterpret_cast<const f32x4*>(bary + (size_t)p * 12);
        bA[j] = __builtin_nontemporal_load(bp + 0);
        bB[j] = __builtin_nontemporal_load(bp + 1);
        bC[j] = __builtin_nontemporal_load(bp + 2);
    }

    // ---- Phase B: weights + gather addresses ----
    float wn[2][4], delta[2];
    const u32x4* rp[2][4];
#pragma unroll
    for (int j = 0; j < 2; ++j) {
        const int fidx[4] = {f4[j].x, f4[j].y, f4[j].z, f4[j].w};
        const float d[4] = {dv[j].x, dv[j].y, dv[j].z, dv[j].w};
        const float z[4] = {zv[j].x, zv[j].y, zv[j].z, zv[j].w};
        float prob[4], zinv[4], zmax = EPS_;
#pragma unroll
        for (int k = 0; k < K_; ++k) {
            const bool valid = fidx[k] >= 0;
            prob[k] = valid ? 1.0f / (1.0f + __expf(d[k] * (1.0f / SIGMA_))) : 0.0f;
            zinv[k] = valid ? (ZFAR_ - z[k]) * (1.0f / (ZFAR_ - ZNEAR_)) : 0.0f;
            zmax = fmaxf(zmax, zinv[k]);
        }
        delta[j] = fmaxf(__expf((EPS_ - zmax) * (1.0f / GAMMA_)), EPS_);
#pragma unroll
        for (int k = 0; k < K_; ++k) {
            wn[j][k] = prob[k] * __expf((zinv[k] - zmax) * (1.0f / GAMMA_));
            rp[j][k] = reinterpret_cast<const u32x4*>(fnorm) +
                       ((wn[j][k] != 0.0f) ? fidx[k] : 0);
        }
    }

    // ---- Phase C: all 8 slot gathers in flight (16B each) ----
    u32x4 row[2][4];
#pragma unroll
    for (int j = 0; j < 2; ++j)
#pragma unroll
        for (int k = 0; k < K_; ++k)
            row[j][k] = *rp[j][k];

    // ---- Phase D: decode + blend + store ----
#pragma unroll
    for (int j = 0; j < 2; ++j) {
        const float bb[12] = {bA[j].x, bA[j].y, bA[j].z, bA[j].w,
                              bB[j].x, bB[j].y, bB[j].z, bB[j].w,
                              bC[j].x, bC[j].y, bC[j].z, bC[j].w};
        float acc0 = 0.f, acc1 = 0.f, acc2 = 0.f, wsum = 0.f;
#pragma unroll
        for (int k = 0; k < K_; ++k) {
            const float w = wn[j][k];
            wsum += w;
            const f32x3 n0 = oct_decode(row[j][k].x);
            const f32x3 n1 = oct_decode(row[j][k].y);
            const f32x3 n2 = oct_decode(row[j][k].z);
            const float b0 = bb[3 * k + 0], b1 = bb[3 * k + 1], b2 = bb[3 * k + 2];
            acc0 += w * (b0 * n0.x + b1 * n1.x + b2 * n2.x);
            acc1 += w * (b0 * n0.y + b1 * n1.y + b2 * n2.y);
            acc2 += w * (b0 * n0.z + b1 * n1.z + b2 * n2.z);
        }
        const float inv_denom = 1.0f / (wsum + delta[j]);
        const float r0 = (acc0 + delta[j]) * inv_denom;   // bg = (1,1,1)
        const float r1 = (acc1 + delta[j]) * inv_denom;
        const float r2 = (acc2 + delta[j]) * inv_denom;
        const float nrm = fmaxf(sqrtf(r0 * r0 + r1 * r1 + r2 * r2), 1e-12f);
        const float inv = 1.0f / nrm;
        __builtin_nontemporal_store(
            f32x3{r0 * inv, r1 * inv, r2 * inv},
            reinterpret_cast<f32x3*>(out + (size_t)pp[j] * 3));
    }
}

// Fallback (proven R5 structure, exact fp32 path) if ws can't hold the table.
__global__ __launch_bounds__(256) void normal_shader_fused_kernel(
    const float* __restrict__ vnorm,
    const float* __restrict__ bary,
    const float* __restrict__ dists,
    const float* __restrict__ zbuf,
    const int*   __restrict__ faces,
    const int*   __restrict__ ptf,
    float*       __restrict__ out,
    int P)
{
    const int p = blockIdx.x * blockDim.x + threadIdx.x;
    if (p >= P) return;
    const i32x4 f4 = reinterpret_cast<const i32x4*>(ptf)[p];
    const int fidx[4] = {f4.x, f4.y, f4.z, f4.w};
    const f32x4 dv = reinterpret_cast<const f32x4*>(dists)[p];
    const f32x4 zv = reinterpret_cast<const f32x4*>(zbuf)[p];
    const float d[4] = {dv.x, dv.y, dv.z, dv.w};
    const float z[4] = {zv.x, zv.y, zv.z, zv.w};
    float prob[4], zinv[4], zmax = EPS_;
#pragma unroll
    for (int k = 0; k < K_; ++k) {
        const bool valid = fidx[k] >= 0;
        prob[k] = valid ? 1.0f / (1.0f + __expf(d[k] * (1.0f / SIGMA_))) : 0.0f;
        zinv[k] = valid ? (ZFAR_ - z[k]) * (1.0f / (ZFAR_ - ZNEAR_)) : 0.0f;
        zmax = fmaxf(zmax, zinv[k]);
    }
    const float delta = fmaxf(__expf((EPS_ - zmax) * (1.0f / GAMMA_)), EPS_);
    float wn[4];
#pragma unroll
    for (int k = 0; k < K_; ++k) wn[k] = prob[k] * __expf((zinv[k] - zmax) * (1.0f / GAMMA_));
    int cl[4];
#pragma unroll
    for (int k = 0; k < K_; ++k) cl[k] = (wn[k] != 0.0f) ? fidx[k] : 0;
    i32x4 fv[4];
#pragma unroll
    for (int k = 0; k < K_; ++k) fv[k] = *reinterpret_cast<const i32x4*>(faces + 3 * (size_t)cl[k]);
    const f32x4* bp = reinterpret_cast<const f32x4*>(bary + (size_t)p * 12);
    const f32x4 bA = bp[0], bB = bp[1], bC = bp[2];
    const float bb[12] = {bA.x, bA.y, bA.z, bA.w, bB.x, bB.y, bB.z, bB.w, bC.x, bC.y, bC.z, bC.w};
    f32x4 n0[4], n1[4], n2[4];
#pragma unroll
    for (int k = 0; k < K_; ++k) {
        n0[k] = *reinterpret_cast<const f32x4*>(vnorm + 3 * (size_t)fv[k].x);
        n1[k] = *reinterpret_cast<const f32x4*>(vnorm + 3 * (size_t)fv[k].y);
        n2[k] = *reinterpret_cast<const f32x4*>(vnorm + 3 * (size_t)fv[k].z);
    }
    float acc0 = 0.f, acc1 = 0.f, acc2 = 0.f, wsum = 0.f;
#pragma unroll
    for (int k = 0; k < K_; ++k) {
        wsum += wn[k];
        const float b0 = bb[3 * k], b1 = bb[3 * k + 1], b2 = bb[3 * k + 2];
        acc0 += wn[k] * (b0 * n0[k].x + b1 * n1[k].x + b2 * n2[k].x);
        acc1 += wn[k] * (b0 * n0[k].y + b1 * n1[k].y + b2 * n2[k].y);
        acc2 += wn[k] * (b0 * n0[k].z + b1 * n1[k].z + b2 * n2[k].z);
    }
    const float inv_denom = 1.0f / (wsum + delta);
    const float r0 = (acc0 + delta) * inv_denom;
    const float r1 = (acc1 + delta) * inv_denom;
    const float r2 = (acc2 + delta) * inv_denom;
    const float nrm = fmaxf(sqrtf(r0 * r0 + r1 * r1 + r2 * r2), 1e-12f);
    const float inv = 1.0f / nrm;
    float* op = out + (size_t)p * 3;
    op[0] = r0 * inv; op[1] = r1 * inv; op[2] = r2 * inv;
}

extern "C" void kernel_launch(void* const* d_in, const int* in_sizes, int n_in,
                              void* d_out, int out_size, void* d_ws, size_t ws_size,
                              hipStream_t stream) {
    // setup_inputs order: verts(0, unused), vertex_normals(1), bary_coords(2),
    // dists(3), zbuf(4), faces(5), pix_to_face(6)
    const float* vnorm = (const float*)d_in[1];
    const float* bary  = (const float*)d_in[2];
    const float* dists = (const float*)d_in[3];
    const float* zbuf  = (const float*)d_in[4];
    const int*   faces = (const int*)d_in[5];
    const int*   ptf   = (const int*)d_in[6];
    float*       out   = (float*)d_out;

    const int P = N_ * H_ * W_;
    const size_t table_bytes = (size_t)F_ * 16;  // 3.2 MB (16B oct rows)

    if (ws_size >= table_bytes) {
        unsigned int* fnorm = (unsigned int*)d_ws;
        hipLaunchKernelGGL(build_fnorm_kernel,
                           dim3((F_ + 255) / 256), dim3(256), 0, stream,
                           vnorm, faces, fnorm);
        hipLaunchKernelGGL(normal_shader_kernel,
                           dim3(((P >> 1) + 255) / 256), dim3(256), 0, stream,
                           fnorm, bary, dists, zbuf, ptf, out, P);
    } else {
        hipLaunchKernelGGL(normal_shader_fused_kernel,
                           dim3((P + 255) / 256), dim3(256), 0, stream,
                           vnorm, bary, dists, zbuf, faces, ptf, out, P);
    }
}